// Round 11
// baseline (223.655 us; speedup 1.0000x reference)
//
#include <hip/hip_runtime.h>
#include <math.h>

// Problem constants
#define NB 16
#define NL 128
#define DIN 512
#define NH 256
#define NTAGS 45
#define NM (NB*NL)          // 2048 rows
#define NJ (NL+1)           // 129 arc columns

// ws layout (floats)
#define H_OFF     0                        // 2 slabs of NM*NH (k1 K-split partials)
#define U_OFF     (2*NM*NH)                // 1 slab  (u = hidden@Wa + bp)
#define HV_OFF    (3*NM*NH)                // 1 slab  (hv = hidden@Wb)
#define VROOT_OFF (4*NM*NH)                // NH
#define ACC_OFF   (VROOT_OFF + NH)         // [0]=loss sum, [1]=done counter (int)

// ---------------------------------------------------------------------------
// Kernel 1: hidden partials, K-split x2.  h_z = C[:, z*256:+256] @ W1[z*256:+256,:]
// 32x64 tile, 2x4/thread, BK=16, reg-staged dbuf pipeline. grid (64,4,2) =
// 512 blocks -> 2 blocks/CU, 2 waves/SIMD. bias+relu deferred to K2.
// Blocks (x==63, z==1) append the vroot epilogue. Block 0 zeroes accum+counter.
// ---------------------------------------------------------------------------
__global__ __launch_bounds__(256) void gemm_hidden(
    const float* __restrict__ A,    // 2048 x 512
    const float* __restrict__ W,    // 512 x 256
    const float* __restrict__ Wp,   // 512 x 256 (for vroot epilogue)
    const float* __restrict__ root, // 256
    float* __restrict__ h,          // 2 x 2048 x 256 partials
    float* __restrict__ vroot,      // 256
    float* __restrict__ accum)
{
    __shared__ float As[2][16][36];   // [buf][k][m], m=32 (+4 pad)
    __shared__ float Bs[2][16][68];   // [buf][k][n], n=64 (+4 pad)
    __shared__ float part[4][64];     // vroot epilogue scratch
    int m0 = blockIdx.x * 32;
    int n0 = blockIdx.y * 64;
    int kbase = blockIdx.z * 256;
    int tid = threadIdx.x;
    if (blockIdx.x == 0 && blockIdx.y == 0 && blockIdx.z == 0 && tid == 0) {
        accum[0] = 0.f;
        ((int*)accum)[1] = 0;
    }
    int lm = tid >> 2, lk = (tid & 3) * 4;      // A-stage (tid<128): 32 rows x 16 k
    int bk = tid >> 4, bn = (tid & 15) * 4;     // B-stage: 16 k x 64 n
    int tm = tid >> 4, tn = tid & 15;           // compute: 2 rows x 4 cols
    float acc[2][4] = {{0.f}};
    float4 a_r, b_r;

    auto LOADK = [&](int c) {
        int k0 = kbase + c * 16;
        if (tid < 128)
            a_r = *(const float4*)&A[(size_t)(m0 + lm) * DIN + k0 + lk];
        b_r = *(const float4*)&W[(size_t)(k0 + bk) * NH + n0 + bn];
    };
    auto WRITE = [&](int buf) {
        if (tid < 128) {
            As[buf][lk + 0][lm] = a_r.x; As[buf][lk + 1][lm] = a_r.y;
            As[buf][lk + 2][lm] = a_r.z; As[buf][lk + 3][lm] = a_r.w;
        }
        *(float4*)&Bs[buf][bk][bn] = b_r;
    };

    LOADK(0);
    WRITE(0);
    LOADK(1);
    __syncthreads();
    for (int c = 0; c < 16; ++c) {
        int buf = c & 1;
        #pragma unroll
        for (int kk = 0; kk < 16; kk++) {
            float2 a2 = *(const float2*)&As[buf][kk][tm * 2];
            float4 bv = *(const float4*)&Bs[buf][kk][tn * 4];
            float ar[2] = {a2.x, a2.y};
            float br[4] = {bv.x, bv.y, bv.z, bv.w};
            #pragma unroll
            for (int r = 0; r < 2; r++)
                #pragma unroll
                for (int cc = 0; cc < 4; cc++)
                    acc[r][cc] = fmaf(ar[r], br[cc], acc[r][cc]);
        }
        if (c < 15) {
            WRITE(buf ^ 1);          // stage chunk c+1 (loads issued iter c-1)
            if (c < 14) LOADK(c + 2);
            __syncthreads();
        }
    }
    float* hz = h + (size_t)blockIdx.z * NM * NH;
    int col = n0 + tn * 4;
    #pragma unroll
    for (int r = 0; r < 2; r++) {
        int row = m0 + tm * 2 + r;
        *(float4*)&hz[(size_t)row * NH + col] =
            make_float4(acc[r][0], acc[r][1], acc[r][2], acc[r][3]);
    }

    // ---- vroot epilogue on 4 blocks (x==63, z==1): cols n0..n0+63 ----
    if (blockIdx.x == 63 && blockIdx.z == 1) {
        __syncthreads();
        int vcol = n0 + (tid & 63);
        int kc = tid >> 6;
        float p = 0.f;
        #pragma unroll 8
        for (int c = kc * 64; c < kc * 64 + 64; c++)
            p += root[c] * Wp[(size_t)(NH + c) * NH + vcol];
        part[kc][tid & 63] = p;
        __syncthreads();
        if (tid < 64)
            vroot[n0 + tid] = part[0][tid] + part[1][tid]
                            + part[2][tid] + part[3][tid];
    }
}

// ---------------------------------------------------------------------------
// Kernel 2: u = hidden@Wa + bp ; hv = hidden@Wb
// hidden reconstructed on the fly: relu(h0 + h1 + b1) during A-stage.
// Full K=256 (single u/hv slabs; bp folded). 64x32 tile, 2x4/thread, BK=16,
// reg-staged dbuf pipeline. grid (32,16) = 512 blocks -> 2 blocks/CU.
// ---------------------------------------------------------------------------
__global__ __launch_bounds__(256) void gemm_uv(
    const float* __restrict__ h,      // 2 x 2048 x 256 partials
    const float* __restrict__ b1,     // 256 (hidden bias)
    const float* __restrict__ Wp,     // 512 x 256
    const float* __restrict__ bp,     // 256 (pair bias)
    float* __restrict__ u,            // 2048 x 256
    float* __restrict__ hv)           // 2048 x 256
{
    __shared__ float As[2][16][68];   // [buf][k][m], m=64 (+4 pad)
    __shared__ float Bs[2][16][36];   // [buf][k][n], n=32 (+4 pad)
    int m0 = blockIdx.x * 64;
    int n0 = blockIdx.y * 32;
    int tid = threadIdx.x;
    bool isU = (n0 < NH);
    int arow = tid >> 2, akq = (tid & 3) * 4;   // A-stage: 64 rows x 16 k
    int bk = tid >> 3, bn = (tid & 7) * 4;      // B-stage (tid<128): 16 k x 32 n
    int tm = tid >> 3, tn = tid & 7;            // compute: 2 rows x 4 cols
    float acc[2][4] = {{0.f}};
    float4 ha_r, hb_r, bi_r, b_r;

    auto LOADK = [&](int c) {
        int k0 = c * 16;
        size_t base = (size_t)(m0 + arow) * NH + k0 + akq;
        ha_r = *(const float4*)&h[base];
        hb_r = *(const float4*)&h[base + (size_t)NM * NH];
        bi_r = *(const float4*)&b1[k0 + akq];
        if (tid < 128) {
            int ck = k0 + bk;
            if (isU) b_r = *(const float4*)&Wp[(size_t)ck * NH + n0 + bn];
            else     b_r = *(const float4*)&Wp[(size_t)(NH + ck) * NH + (n0 - NH) + bn];
        }
    };
    auto WRITE = [&](int buf) {
        As[buf][akq + 0][arow] = fmaxf(ha_r.x + hb_r.x + bi_r.x, 0.f);
        As[buf][akq + 1][arow] = fmaxf(ha_r.y + hb_r.y + bi_r.y, 0.f);
        As[buf][akq + 2][arow] = fmaxf(ha_r.z + hb_r.z + bi_r.z, 0.f);
        As[buf][akq + 3][arow] = fmaxf(ha_r.w + hb_r.w + bi_r.w, 0.f);
        if (tid < 128)
            *(float4*)&Bs[buf][bk][bn] = b_r;
    };

    LOADK(0);
    WRITE(0);
    LOADK(1);
    __syncthreads();
    for (int c = 0; c < 16; ++c) {
        int buf = c & 1;
        #pragma unroll
        for (int kk = 0; kk < 16; kk++) {
            float2 a2 = *(const float2*)&As[buf][kk][tm * 2];
            float4 bv = *(const float4*)&Bs[buf][kk][tn * 4];
            float ar[2] = {a2.x, a2.y};
            float br[4] = {bv.x, bv.y, bv.z, bv.w};
            #pragma unroll
            for (int r = 0; r < 2; r++)
                #pragma unroll
                for (int cc = 0; cc < 4; cc++)
                    acc[r][cc] = fmaf(ar[r], br[cc], acc[r][cc]);
        }
        if (c < 15) {
            WRITE(buf ^ 1);
            if (c < 14) LOADK(c + 2);
            __syncthreads();
        }
    }
    if (isU) {
        int col = n0 + tn * 4;
        float4 bb = *(const float4*)&bp[col];
        #pragma unroll
        for (int r = 0; r < 2; r++) {
            int row = m0 + tm * 2 + r;
            *(float4*)&u[(size_t)row * NH + col] = make_float4(
                acc[r][0] + bb.x, acc[r][1] + bb.y,
                acc[r][2] + bb.z, acc[r][3] + bb.w);
        }
    } else {
        int col = (n0 - NH) + tn * 4;
        #pragma unroll
        for (int r = 0; r < 2; r++) {
            int row = m0 + tm * 2 + r;
            *(float4*)&hv[(size_t)row * NH + col] = make_float4(
                acc[r][0], acc[r][1], acc[r][2], acc[r][3]);
        }
    }
}

// ---------------------------------------------------------------------------
// Kernel 3 (fused scores+loss+finalize): single-stage full-LDS v-tile +
// READLANE operand path. 8 rows/block (512 thr, wave = row), grid (NB,16)
// = 256 blocks = 1/CU. Only v lives in LDS (132 KB, [kk2][j] float2);
// u-row / W_arc k-pairs are loaded per-lane from global (coalesced, L2-hot)
// and extracted per kk2 via v_readlane (VALU pipe, literal lane index from
// full unroll) -> u2_s/wa2_s/sel2_s and all their DS broadcasts eliminated;
// DS-issue per block drops ~2.5x (was the bottleneck). sel values stay in
// lanes 0..31 registers and are readlane'd by the label loop (readlane is
// exec-independent; lanes 0..31 wrote them under the lane<32 mask).
// One atomicAdd per block; done-counter finalize.
// ---------------------------------------------------------------------------
#define NBLK (NB*16)   // 256

__device__ __forceinline__ float rl(float v, int l) {
    return __int_as_float(__builtin_amdgcn_readlane(__float_as_int(v), l));
}

__global__ __launch_bounds__(512) void score_loss_kernel(
    const float* __restrict__ u, const float* __restrict__ hv,
    const float* __restrict__ vroot, const float* __restrict__ W_arc,
    const float* __restrict__ W_lab, const float* __restrict__ b_lab,
    const int* __restrict__ slens, const int* __restrict__ arcs,
    const int* __restrict__ labels,
    float* __restrict__ accum, float* __restrict__ out)
{
    __shared__ float2 v2_s[128][129];  // [kk2][j]  132,096 B (full K)
    __shared__ float  ce_s[8];
    __shared__ int    arc_s[8], lab_s[8];

    int bb = blockIdx.x;
    int i0 = blockIdx.y * 8;
    int tid = threadIdx.x;
    int w = tid >> 6;          // wave index = local row (0..7)
    int lane = tid & 63;
    int slen = slens[bb];

    if (i0 < slen) {
        if (tid < 8) {
            int rg = bb * NL + i0 + tid;
            arc_s[tid] = arcs[rg];
            lab_s[tid] = labels[rg];
        }

        // ---- per-lane u / wa k-pair registers (all 4 chunks up front;
        //      loads overlap the v-stage). lane&31 clamps: lanes 32-63
        //      duplicate 0-31 (readlane only targets 0..31; lanes<32 use own).
        float2 u_regs[4], wa_regs[4];
        {
            int ll = (lane & 31) * 2;
            const float* urow = u + (size_t)(bb * NL + i0 + w) * NH;
            #pragma unroll
            for (int c = 0; c < 4; ++c) {
                u_regs[c]  = *(const float2*)&urow[c * 64 + ll];
                wa_regs[c] = *(const float2*)&W_arc[c * 64 + ll];
            }
        }

        // ---- v stage (once): hv rows 0..127 -> v cols 1..128; vroot -> col 0.
        {
            int jo  = lane >> 4;         // 0..3
            int kf0 = lane & 15;         // 0..15
            #pragma unroll
            for (int sj = 0; sj < 4; ++sj) {
                int j = sj * 32 + w * 4 + jo;        // hv row 0..127
                const float* src = hv + (size_t)(bb * NL + j) * NH;
                #pragma unroll
                for (int sk = 0; sk < 4; ++sk) {
                    int kf = sk * 16 + kf0;          // float4 col 0..63
                    float4 t4 = *(const float4*)&src[kf * 4];
                    v2_s[2 * kf + 0][j + 1] = make_float2(t4.x, t4.y);
                    v2_s[2 * kf + 1][j + 1] = make_float2(t4.z, t4.w);
                }
            }
            if (w == 0) {                            // vroot -> col 0
                float4 t4 = *(const float4*)&vroot[lane * 4];
                v2_s[2 * lane + 0][0] = make_float2(t4.x, t4.y);
                v2_s[2 * lane + 1][0] = make_float2(t4.z, t4.w);
            }
        }
        __syncthreads();

        float acc1 = 0.f, acc2 = 0.f, s128 = 0.f, lacc = 0.f;
        int a = arc_s[w];

        __builtin_amdgcn_s_setprio(1);
        #pragma unroll
        for (int c = 0; c < 4; ++c) {
            int k0 = c * 64;
            int kb = k0 >> 1;            // base kk2 row in v2_s

            // ---- arc scores: lane covers j=lane and j=lane+64;
            //      u/wa extracted via readlane (VALU), only va/vb hit DS ----
            #pragma unroll
            for (int kk2 = 0; kk2 < 32; ++kk2) {
                float ux = rl(u_regs[c].x, kk2), uy = rl(u_regs[c].y, kk2);
                float wx = rl(wa_regs[c].x, kk2), wy = rl(wa_regs[c].y, kk2);
                float2 va = v2_s[kb + kk2][lane];
                float2 vb = v2_s[kb + kk2][lane + 64];
                acc1 += fmaxf(ux + va.x, 0.f) * wx + fmaxf(uy + va.y, 0.f) * wy;
                acc2 += fmaxf(ux + vb.x, 0.f) * wx + fmaxf(uy + vb.y, 0.f) * wy;
            }
            // ---- j=128 partial + sel (lanes 0..31 own k-pair kk2=lane) ----
            float sel_x = 0.f, sel_y = 0.f;
            if (lane < 32) {
                float2 vv = v2_s[kb + lane][128];
                s128 += fmaxf(u_regs[c].x + vv.x, 0.f) * wa_regs[c].x
                      + fmaxf(u_regs[c].y + vv.y, 0.f) * wa_regs[c].y;
                float2 vs = v2_s[kb + lane][a];
                sel_x = fmaxf(u_regs[c].x + vs.x, 0.f);
                sel_y = fmaxf(u_regs[c].y + vs.y, 0.f);
            }
            // ---- label logit partials: lane = tag; sel via readlane ----
            if (lane < NTAGS) {
                #pragma unroll
                for (int kk2 = 0; kk2 < 32; ++kk2) {
                    float sx = rl(sel_x, kk2), sy = rl(sel_y, kk2);
                    float w0 = W_lab[(size_t)(k0 + 2 * kk2) * NTAGS + lane];
                    float w1 = W_lab[(size_t)(k0 + 2 * kk2 + 1) * NTAGS + lane];
                    lacc = fmaf(sx, w0, fmaf(sy, w1, lacc));
                }
            }
        }
        __builtin_amdgcn_s_setprio(0);

        // ---- arc softmax CE (full-wave shuffles) ----
        float s128t = s128;
        #pragma unroll
        for (int off = 32; off > 0; off >>= 1)
            s128t += __shfl_xor(s128t, off);
        float m = fmaxf(acc1, acc2);
        #pragma unroll
        for (int off = 32; off > 0; off >>= 1)
            m = fmaxf(m, __shfl_xor(m, off));
        m = fmaxf(m, s128t);
        float e = expf(acc1 - m) + expf(acc2 - m);
        #pragma unroll
        for (int off = 32; off > 0; off >>= 1)
            e += __shfl_xor(e, off);
        e += expf(s128t - m);
        float cand = (a < 64) ? acc1 : acc2;
        float s_a = __shfl(cand, a & 63, 64);
        if (a == 128) s_a = s128t;
        float arc_ce = (m + logf(e)) - s_a;

        // ---- label softmax CE ----
        float logit = (lane < NTAGS) ? (lacc + b_lab[lane]) : -INFINITY;
        float m2 = logit;
        #pragma unroll
        for (int off = 32; off > 0; off >>= 1)
            m2 = fmaxf(m2, __shfl_xor(m2, off));
        float e2 = (lane < NTAGS) ? expf(logit - m2) : 0.f;
        #pragma unroll
        for (int off = 32; off > 0; off >>= 1)
            e2 += __shfl_xor(e2, off);
        float l_t = __shfl(logit, lab_s[w], 64);
        float lab_ce = (m2 + logf(e2)) - l_t;

        float tot = ((i0 + w) < slen) ? (arc_ce + lab_ce) : 0.f;
        if (lane == 0) ce_s[w] = tot;
        __syncthreads();
        if (tid == 0)
            atomicAdd(accum, ce_s[0] + ce_s[1] + ce_s[2] + ce_s[3]
                           + ce_s[4] + ce_s[5] + ce_s[6] + ce_s[7]);
    }

    // ---- done counter; last block finalizes ----
    if (tid == 0) {
        __threadfence();
        int prev = atomicAdd((int*)accum + 1, 1);
        if (prev == NBLK - 1) {
            int d = 0;
            #pragma unroll
            for (int q = 0; q < NB; ++q) d += slens[q];
            float s = atomicAdd(accum, 0.f);   // coherent read
            out[0] = 0.5f * s / fmaxf((float)d, 1.f);
        }
    }
}

extern "C" void kernel_launch(void* const* d_in, const int* in_sizes, int n_in,
                              void* d_out, int out_size, void* d_ws, size_t ws_size,
                              hipStream_t stream) {
    (void)in_sizes; (void)n_in; (void)out_size; (void)ws_size;
    const float* ctx   = (const float*)d_in[0];
    const int*   slens = (const int*)  d_in[1];
    const int*   arcs  = (const int*)  d_in[2];
    const int*   labs  = (const int*)  d_in[3];
    const float* W1    = (const float*)d_in[4];
    const float* b1    = (const float*)d_in[5];
    const float* root  = (const float*)d_in[6];
    const float* Wp    = (const float*)d_in[7];
    const float* bp    = (const float*)d_in[8];
    const float* W_arc = (const float*)d_in[9];
    // d_in[10] = b_arc: constant shift, cancels in arc log-softmax CE
    const float* W_lab = (const float*)d_in[11];
    const float* b_lab = (const float*)d_in[12];
    float* out = (float*)d_out;

    float* ws    = (float*)d_ws;
    float* h     = ws + H_OFF;
    float* u     = ws + U_OFF;
    float* hv    = ws + HV_OFF;
    float* vroot = ws + VROOT_OFF;
    float* accum = ws + ACC_OFF;

    gemm_hidden<<<dim3(64, 4, 2), 256, 0, stream>>>(ctx, W1, Wp, root, h, vroot, accum);
    gemm_uv<<<dim3(32, 16), 256, 0, stream>>>(h, b1, Wp, bp, u, hv);
    score_loss_kernel<<<dim3(NB, 16), 512, 0, stream>>>(
        u, hv, vroot, W_arc, W_lab, b_lab, slens, arcs, labs, accum, out);
}